// Round 1
// baseline (94.980 us; speedup 1.0000x reference)
//
#include <hip/hip_runtime.h>

// 10-qubit circuit: 10x Rot(phi,theta,omega) (one per wire) + CNOT ring + <X>,<Y>,<Z> on wire 0.
// Strategy:
//  - One wave (64 lanes) per batch state; lane holds 16 complex amps, idx = lane*16 + r.
//    r bits 0..3 = index bits 0..3 = wires 9..6 (in-register gates).
//    lane bits 0..5 = index bits 4..9 = wires 5..0 (cross-lane gates via shfl_xor).
//  - CNOT ring folded into measurement: final[b] = pre[Q(b)], Q(e0) flips wires {0,1}
//    => partner mask on idx = 0x300 = lane-mask 48; sign = parity(idx & 0x1FF).
//      ex = sum_all Re(conj(m)*o); ey = sum_all sgn*Im(conj(m)*o); ez = sum_all sgn*|m|^2.
//  - Gate matrices precomputed by a 1-block setup kernel into d_ws (avoids per-wave trig).

__global__ void qk_setup_gates(const float* __restrict__ w, float* __restrict__ U) {
    int i = threadIdx.x;
    if (i < 10) {
        float phi = w[3 * i + 0];
        float th  = w[3 * i + 1];
        float om  = w[3 * i + 2];
        float c  = cosf(0.5f * th), s  = sinf(0.5f * th);
        float hp = 0.5f * (phi + om), hm = 0.5f * (phi - om);
        float chp = cosf(hp), shp = sinf(hp);
        float chm = cosf(hm), shm = sinf(hm);
        float* u = U + 8 * i;
        // ep = e^{-i hp}, em = e^{+i hm}
        u[0] =  c * chp;  u[1] = -c * shp;   // U00 = ep*c
        u[2] = -s * chm;  u[3] = -s * shm;   // U01 = -em*s
        u[4] =  s * chm;  u[5] = -s * shm;   // U10 = conj(em)*s
        u[6] =  c * chp;  u[7] =  c * shp;   // U11 = conj(ep)*c
    }
}

__global__ __launch_bounds__(256) void qk_sim(const float* __restrict__ x,
                                              const float* __restrict__ Ug,
                                              float* __restrict__ out,
                                              int nstates) {
    int wave = (int)((blockIdx.x * blockDim.x + threadIdx.x) >> 6);
    int lane = threadIdx.x & 63;
    if (wave >= nstates) return;

    // ---- load 16 real amplitudes (idx = lane*16 + r), imag = 0 ----
    const float4* row = (const float4*)(x + (size_t)wave * 1024);
    float re[16], im[16];
#pragma unroll
    for (int k = 0; k < 4; k++) {
        float4 v = row[lane * 4 + k];
        re[4 * k + 0] = v.x; re[4 * k + 1] = v.y;
        re[4 * k + 2] = v.z; re[4 * k + 3] = v.w;
        im[4 * k + 0] = 0.f; im[4 * k + 1] = 0.f;
        im[4 * k + 2] = 0.f; im[4 * k + 3] = 0.f;
    }

    // ---- in-register gates: wires 9,8,7,6  (r-bit rb = 9 - wire) ----
#pragma unroll
    for (int rb = 0; rb < 4; rb++) {
        const float* u = Ug + 8 * (9 - rb);
        float u0 = u[0], u1 = u[1], u2 = u[2], u3 = u[3];
        float u4 = u[4], u5 = u[5], u6 = u[6], u7 = u[7];
#pragma unroll
        for (int r0 = 0; r0 < 16; r0++) {
            if (r0 & (1 << rb)) continue;
            int r1 = r0 | (1 << rb);
            float ar = re[r0], ai = im[r0];
            float br = re[r1], bi = im[r1];
            re[r0] = u0 * ar - u1 * ai + u2 * br - u3 * bi;
            im[r0] = u0 * ai + u1 * ar + u2 * bi + u3 * br;
            re[r1] = u4 * ar - u5 * ai + u6 * br - u7 * bi;
            im[r1] = u4 * ai + u5 * ar + u6 * bi + u7 * br;
        }
    }

    // ---- cross-lane gates: lane-bit l = 0..5 -> wire 5-l ----
#pragma unroll
    for (int l = 0; l < 6; l++) {
        const float* u = Ug + 8 * (5 - l);
        int bit = (lane >> l) & 1;
        // bit==0: new = U00*mine + U01*other ; bit==1: new = U11*mine + U10*other
        float Ar = bit ? u[6] : u[0];
        float Ai = bit ? u[7] : u[1];
        float Br = bit ? u[4] : u[2];
        float Bi = bit ? u[5] : u[3];
#pragma unroll
        for (int r = 0; r < 16; r++) {
            float mr = re[r], mi = im[r];
            float pr = __shfl_xor(mr, 1 << l, 64);
            float pi = __shfl_xor(mi, 1 << l, 64);
            re[r] = Ar * mr - Ai * mi + Br * pr - Bi * pi;
            im[r] = Ar * mi + Ai * mr + Br * pi + Bi * pr;
        }
    }

    // ---- measurement with CNOT ring folded in ----
    // partner: idx ^ 0x300 -> lane ^ 48 ; sign: parity(idx & 0x1FF)
    float ex = 0.f, ey = 0.f, ez = 0.f;
    int lpar = __popc(lane & 31) & 1;
#pragma unroll
    for (int r = 0; r < 16; r++) {
        float mr = re[r], mi = im[r];
        float pr = __shfl_xor(mr, 48, 64);
        float pi = __shfl_xor(mi, 48, 64);
        float sgn = ((lpar ^ (__popc(r) & 1)) != 0) ? -1.f : 1.f;
        ex += mr * pr + mi * pi;          // Re(conj(m) * o)
        ey += sgn * (mr * pi - mi * pr);  // sgn * Im(conj(m) * o)
        ez += sgn * (mr * mr + mi * mi);  // sgn * |m|^2
    }
#pragma unroll
    for (int off = 32; off >= 1; off >>= 1) {
        ex += __shfl_xor(ex, off, 64);
        ey += __shfl_xor(ey, off, 64);
        ez += __shfl_xor(ez, off, 64);
    }
    if (lane == 0) {
        float* o = out + 3 * (size_t)wave;
        o[0] = ex; o[1] = ey; o[2] = ez;
    }
}

extern "C" void kernel_launch(void* const* d_in, const int* in_sizes, int n_in,
                              void* d_out, int out_size, void* d_ws, size_t ws_size,
                              hipStream_t stream) {
    const float* patch   = (const float*)d_in[0];
    const float* weights = (const float*)d_in[1];
    float* out = (float*)d_out;
    float* Ug  = (float*)d_ws;  // 10 * 8 floats

    int nstates = in_sizes[0] / 1024;  // 8192

    qk_setup_gates<<<1, 64, 0, stream>>>(weights, Ug);

    int waves_per_block = 256 / 64;
    int nblocks = (nstates + waves_per_block - 1) / waves_per_block;
    qk_sim<<<nblocks, 256, 0, stream>>>(patch, Ug, out, nstates);
}

// Round 2
// 93.893 us; speedup vs baseline: 1.0116x; 1.0116x over previous
//
#include <hip/hip_runtime.h>

// 10-qubit circuit: 10x Rot(phi,theta,omega) + CNOT ring + <X>,<Y>,<Z> on wire 0.
//
// Rot(phi,theta,omega) = RZ(omega) RY(theta) RZ(phi); 1q gates commute across wires.
// Circuit = D_omega * RY_layer * D_phi applied to a REAL input state:
//  - D_phi: psi *= e^{i alpha(idx)}, alpha = sum_w bit_w(idx)*phi_w (global phase dropped).
//    Factors as e^{i aL(lane)} * e^{i aR(r)} -> L[64] + R[16] tables from setup kernel.
//  - RY layer: real 2x2 rotations [[c,-s],[s,c]] -> half the FLOPs of complex gates.
//  - D_omega: folded into measurement. ez uses |psi|^2 (phases cancel); ex/ey partner
//    idx^0x300 flips wires {0,1} only -> relative phase Delta = (1-2b9)w0+(1-2b8)w1 is
//    lane-uniform (lane bits 4,5) -> 4-entry T4 table applied after the r-loop.
//  - CNOT ring folded into measurement (verified in R1): partner lane^48,
//    sign = parity(lane&31) ^ parity(r).
// Layout: one wave per state; lane holds 16 complex amps, idx = lane*16 + r.
// idx bit b <-> wire 9-b: r bits 0..3 = wires 9..6 (in-register), lane bits 0..5 = wires 5..0.

__global__ void qk_setup(const float* __restrict__ w, float* __restrict__ ws) {
    int t = threadIdx.x;
    // CS[20] @0: (cos(theta_w/2), sin(theta_w/2)) per wire
    if (t < 10) {
        float th = w[3 * t + 1];
        ws[2 * t]     = cosf(0.5f * th);
        ws[2 * t + 1] = sinf(0.5f * th);
    }
    // R[32] @32: r-bit j -> wire 9-j ; aR = sum bit_j * phi_{9-j}
    if (t < 16) {
        float a = 0.f;
        for (int j = 0; j < 4; j++) if ((t >> j) & 1) a += w[3 * (9 - j)];
        ws[32 + 2 * t]     = cosf(a);
        ws[32 + 2 * t + 1] = sinf(a);
    }
    // L[128] @64: lane bit j -> wire 5-j ; aL = sum bit_j * phi_{5-j}
    {
        float a = 0.f;
        for (int j = 0; j < 6; j++) if ((t >> j) & 1) a += w[3 * (5 - j)];
        ws[64 + 2 * t]     = cosf(a);
        ws[64 + 2 * t + 1] = sinf(a);
    }
    // T4[8] @192: j bit0 = b8(wire1), bit1 = b9(wire0); Delta = (1-2b9)*omega_0 + (1-2b8)*omega_1
    if (t < 4) {
        float d = (1.f - 2.f * ((t >> 1) & 1)) * w[2] + (1.f - 2.f * (t & 1)) * w[5];
        ws[192 + 2 * t]     = cosf(d);
        ws[192 + 2 * t + 1] = sinf(d);
    }
}

__global__ __launch_bounds__(256) void qk_sim(const float* __restrict__ x,
                                              const float* __restrict__ ws,
                                              float* __restrict__ out,
                                              int nstates) {
    int wave = (int)((blockIdx.x * blockDim.x + threadIdx.x) >> 6);
    int lane = threadIdx.x & 63;
    if (wave >= nstates) return;

    const float* CS = ws;        // theta cos/sin per wire
    const float* R  = ws + 32;   // r-phase table (wave-uniform -> s_load)
    const float* L  = ws + 64;   // lane-phase table
    const float* T4 = ws + 192;  // omega fold table

    float Lr = L[2 * lane], Li = L[2 * lane + 1];

    // ---- load 16 real amps, apply D_phi: amp = x * e^{i(aL+aR)} ----
    const float4* row = (const float4*)(x + (size_t)wave * 1024);
    float re[16], im[16];
#pragma unroll
    for (int k = 0; k < 4; k++) {
        float4 v = row[lane * 4 + k];
        float xs0 = v.x, xs1 = v.y, xs2 = v.z, xs3 = v.w;
        float xv[4] = {xs0, xs1, xs2, xs3};
#pragma unroll
        for (int j = 0; j < 4; j++) {
            int r = 4 * k + j;
            float ar = xv[j] * R[2 * r];
            float ai = xv[j] * R[2 * r + 1];
            re[r] = Lr * ar - Li * ai;
            im[r] = Lr * ai + Li * ar;
        }
    }

    // ---- in-register RY: r-bit rb -> wire 9-rb ----
#pragma unroll
    for (int rb = 0; rb < 4; rb++) {
        float c = CS[2 * (9 - rb)], s = CS[2 * (9 - rb) + 1];
#pragma unroll
        for (int r0 = 0; r0 < 16; r0++) {
            if (r0 & (1 << rb)) continue;
            int r1 = r0 | (1 << rb);
            float a0r = re[r0], a0i = im[r0];
            float a1r = re[r1], a1i = im[r1];
            re[r0] = c * a0r - s * a1r;  im[r0] = c * a0i - s * a1i;
            re[r1] = s * a0r + c * a1r;  im[r1] = s * a0i + c * a1i;
        }
    }

    // ---- cross-lane RY: lane bit l -> wire 5-l ----
    // bit==0: new = c*m - s*p ; bit==1: new = c*m + s*p
#pragma unroll
    for (int l = 0; l < 6; l++) {
        float c = CS[2 * (5 - l)], s = CS[2 * (5 - l) + 1];
        float ss = ((lane >> l) & 1) ? s : -s;
#pragma unroll
        for (int r = 0; r < 16; r++) {
            float mr = re[r], mi = im[r];
            float pr = __shfl_xor(mr, 1 << l, 64);
            float pi = __shfl_xor(mi, 1 << l, 64);
            re[r] = c * mr + ss * pr;
            im[r] = c * mi + ss * pi;
        }
    }

    // ---- measurement: CNOT ring + D_omega folded ----
    float zxr = 0.f, zxi = 0.f, zyr = 0.f, zyi = 0.f, ez = 0.f;
#pragma unroll
    for (int r = 0; r < 16; r++) {
        float mr = re[r], mi = im[r];
        float pr = __shfl_xor(mr, 48, 64);
        float pi = __shfl_xor(mi, 48, 64);
        float cr = mr * pr + mi * pi;   // Re(conj(m)*p)
        float ci = mr * pi - mi * pr;   // Im(conj(m)*p)
        zxr += cr; zxi += ci;
        if (__popc(r) & 1) { zyr -= cr; zyi -= ci; ez -= mr * mr + mi * mi; }
        else               { zyr += cr; zyi += ci; ez += mr * mr + mi * mi; }
    }
    int j4 = (lane >> 4) & 3;
    float cD = T4[2 * j4], sD = T4[2 * j4 + 1];
    float lsgn = (__popc(lane & 31) & 1) ? -1.f : 1.f;
    float ex  = cD * zxr - sD * zxi;                 // Re(e^{iD} * zx)
    float ey  = lsgn * (cD * zyi + sD * zyr);        // lsgn * Im(e^{iD} * zy)
    float ezl = lsgn * ez;

#pragma unroll
    for (int off = 32; off >= 1; off >>= 1) {
        ex  += __shfl_xor(ex,  off, 64);
        ey  += __shfl_xor(ey,  off, 64);
        ezl += __shfl_xor(ezl, off, 64);
    }
    if (lane == 0) {
        float* o = out + 3 * (size_t)wave;
        o[0] = ex; o[1] = ey; o[2] = ezl;
    }
}

extern "C" void kernel_launch(void* const* d_in, const int* in_sizes, int n_in,
                              void* d_out, int out_size, void* d_ws, size_t ws_size,
                              hipStream_t stream) {
    const float* patch   = (const float*)d_in[0];
    const float* weights = (const float*)d_in[1];
    float* out = (float*)d_out;
    float* ws  = (float*)d_ws;  // 200 floats of tables

    int nstates = in_sizes[0] / 1024;  // 8192

    qk_setup<<<1, 64, 0, stream>>>(weights, ws);

    int nblocks = nstates / 4;  // 4 waves (256 threads) per block
    qk_sim<<<nblocks, 256, 0, stream>>>(patch, ws, out, nstates);
}

// Round 4
// 85.916 us; speedup vs baseline: 1.1055x; 1.0928x over previous
//
#include <hip/hip_runtime.h>

// 10-qubit circuit: 10x Rot(phi,theta,omega) + CNOT ring + <X>,<Y>,<Z> on wire 0.
//
// Circuit = D_omega * RY_layer * D_phi on a REAL input (Rot = RZ(om) RY(th) RZ(phi),
// 1q gates commute across wires). CNOT ring + D_omega folded into measurement.
//
// Layout (R3): one wave per state. Lane holds 16 complex amps in slots s = h*4+q:
//   idx = h*256 + lane*4 + q   (h = idx[9:8], lane = idx[7:2], q = idx[1:0])
//   wire w <-> idx bit 9-w:
//     slot bit0 = wire9, bit1 = wire8, bit2 = wire1, bit3 = wire0   (in-register gates)
//     lane bit l = wire 7-l, l=0..5                                  (cross-lane gates)
// Measurement partner idx^0x300 (flip wires 0,1) = slot^12 -> NO shuffles.
// Cross-lane exchanges: masks 1,2,4,8 via DPP (VALU pipe, per-SIMD) instead of the
// per-CU shared DS pipe; only masks 16 (ds_swizzle) and 32 (shfl) remain on DS.
// R2 was DS-pipe bound (halving VALU moved dur by 1%): DS ops/lane 242 -> ~70.

template <int CTRL>
__device__ __forceinline__ float dppf(float x) {
    return __int_as_float(__builtin_amdgcn_update_dpp(
        __float_as_int(x), __float_as_int(x), CTRL, 0xF, 0xF, true));
}

template <int MASK>
__device__ __forceinline__ float lxor(float x) {
    if constexpr (MASK == 1)  return dppf<0xB1>(x);                 // quad_perm [1,0,3,2]
    else if constexpr (MASK == 2)  return dppf<0x4E>(x);            // quad_perm [2,3,0,1]
    else if constexpr (MASK == 4)  return dppf<0x141>(dppf<0x1B>(x)); // xor7 o xor3 = xor4
    else if constexpr (MASK == 8)  return dppf<0x128>(x);           // row_ror:8 within 16
    else if constexpr (MASK == 16)
        return __int_as_float(__builtin_amdgcn_ds_swizzle(__float_as_int(x), 0x401F));
    else return __shfl_xor(x, MASK, 64);                            // mask 32: ds_bpermute
}

__global__ void qk_setup(const float* __restrict__ w, float* __restrict__ ws) {
    int t = threadIdx.x;  // 0..1023
    // P[2048] @0: e^{i alpha(idx)}, alpha = sum_w bit_w(idx)*phi_w (wire w <-> idx bit 9-w)
    float a = 0.f;
    for (int wq = 0; wq < 10; wq++)
        if ((t >> (9 - wq)) & 1) a += w[3 * wq];
    ws[2 * t]     = cosf(a);
    ws[2 * t + 1] = sinf(a);
    // CS[20] @2048: (cos(th/2), sin(th/2)) per wire
    if (t < 10) {
        float th = w[3 * t + 1];
        ws[2048 + 2 * t]     = cosf(0.5f * th);
        ws[2048 + 2 * t + 1] = sinf(0.5f * th);
    }
    // T4[8] @2068: h = idx[9:8] = (b9,b8); Delta = (1-2*b9)*omega0 + (1-2*b8)*omega1
    if (t < 4) {
        float d = (1.f - 2.f * ((t >> 1) & 1)) * w[2] + (1.f - 2.f * (t & 1)) * w[5];
        ws[2068 + 2 * t]     = cosf(d);
        ws[2068 + 2 * t + 1] = sinf(d);
    }
}

__device__ __forceinline__ void rgate(float (&re)[16], float (&im)[16], int bit,
                                      float c, float s) {
#pragma unroll
    for (int s0 = 0; s0 < 16; s0++) {
        if (s0 & bit) continue;
        int s1 = s0 | bit;
        float a0r = re[s0], a0i = im[s0];
        float a1r = re[s1], a1i = im[s1];
        re[s0] = c * a0r - s * a1r;  im[s0] = c * a0i - s * a1i;
        re[s1] = s * a0r + c * a1r;  im[s1] = s * a0i + c * a1i;
    }
}

template <int MASK>
__device__ __forceinline__ void xgate(float (&re)[16], float (&im)[16],
                                      float c, float ss) {
#pragma unroll
    for (int r = 0; r < 16; r++) {
        float pr = lxor<MASK>(re[r]);
        float pi = lxor<MASK>(im[r]);
        re[r] = c * re[r] + ss * pr;
        im[r] = c * im[r] + ss * pi;
    }
}

__global__ __launch_bounds__(256) void qk_sim(const float* __restrict__ x,
                                              const float* __restrict__ ws,
                                              float* __restrict__ out,
                                              int nstates) {
    int wave = (int)((blockIdx.x * blockDim.x + threadIdx.x) >> 6);
    int lane = threadIdx.x & 63;
    if (wave >= nstates) return;

    const float* CS = ws + 2048;
    const float* T4 = ws + 2068;

    // ---- load + D_phi: amp[s] = x[idx] * e^{i alpha(idx)} ----
    const float4* rowx = (const float4*)(x + (size_t)wave * 1024);
    const float4* Pt   = (const float4*)ws;  // P as (c,s) pairs -> 2 idx per float4
    float re[16], im[16];
#pragma unroll
    for (int h = 0; h < 4; h++) {
        float4 v  = rowx[h * 64 + lane];
        float4 p0 = Pt[h * 128 + lane * 2];
        float4 p1 = Pt[h * 128 + lane * 2 + 1];
        re[h * 4 + 0] = v.x * p0.x;  im[h * 4 + 0] = v.x * p0.y;
        re[h * 4 + 1] = v.y * p0.z;  im[h * 4 + 1] = v.y * p0.w;
        re[h * 4 + 2] = v.z * p1.x;  im[h * 4 + 2] = v.z * p1.y;
        re[h * 4 + 3] = v.w * p1.z;  im[h * 4 + 3] = v.w * p1.w;
    }

    // ---- in-register RY: slot bit0=wire9, bit1=wire8, bit2=wire1, bit3=wire0 ----
    rgate(re, im, 1, CS[2 * 9], CS[2 * 9 + 1]);
    rgate(re, im, 2, CS[2 * 8], CS[2 * 8 + 1]);
    rgate(re, im, 4, CS[2 * 1], CS[2 * 1 + 1]);
    rgate(re, im, 8, CS[2 * 0], CS[2 * 0 + 1]);

    // ---- cross-lane RY: lane bit l -> wire 7-l ; bit=0: c*m - s*p, bit=1: c*m + s*p ----
    {
        float s7 = CS[2 * 7 + 1], s6 = CS[2 * 6 + 1], s5 = CS[2 * 5 + 1];
        float s4 = CS[2 * 4 + 1], s3 = CS[2 * 3 + 1], s2 = CS[2 * 2 + 1];
        xgate<1> (re, im, CS[2 * 7], (lane & 1)  ? s7 : -s7);
        xgate<2> (re, im, CS[2 * 6], (lane & 2)  ? s6 : -s6);
        xgate<4> (re, im, CS[2 * 5], (lane & 4)  ? s5 : -s5);
        xgate<8> (re, im, CS[2 * 4], (lane & 8)  ? s4 : -s4);
        xgate<16>(re, im, CS[2 * 3], (lane & 16) ? s3 : -s3);
        xgate<32>(re, im, CS[2 * 2], (lane & 32) ? s2 : -s2);
    }

    // ---- measurement: CNOT ring + D_omega folded; partner = slot^12 (in-register) ----
    // ex = 2*sum_{h in 0,1; q} [cD*cr - sD*ci]
    // ey = 2*psgn*sum_{h in 0,1; q} (+/-)[cD*ci + sD*cr],  +/- = (h&1)^parity(q)
    // ez = psgn*sum_{all s} (+/-)|amp|^2,                   +/- = (h&1)^parity(q)
    float ex2 = 0.f, ey2 = 0.f, ez16 = 0.f;
#pragma unroll
    for (int h = 0; h < 2; h++) {
        float cD = T4[2 * h], sD = T4[2 * h + 1];
#pragma unroll
        for (int q = 0; q < 4; q++) {
            int s  = h * 4 + q;
            int sp = s ^ 12;
            float mr = re[s], mi = im[s];
            float pr = re[sp], pi = im[sp];
            float cr = mr * pr + mi * pi;
            float ci = mr * pi - mi * pr;
            ex2 += cD * cr - sD * ci;
            float t = cD * ci + sD * cr;
            if ((h ^ (__popc(q) & 1)) & 1) ey2 -= t; else ey2 += t;
        }
    }
#pragma unroll
    for (int s = 0; s < 16; s++) {
        float n = re[s] * re[s] + im[s] * im[s];
        if ((((s >> 2) & 1) ^ (__popc(s & 3) & 1)) & 1) ez16 -= n; else ez16 += n;
    }
    float psgn = (__popc(lane) & 1) ? -1.f : 1.f;
    float ex = 2.f * ex2;
    float ey = 2.f * psgn * ey2;
    float ez = psgn * ez16;

    // ---- wave reduction (DPP for 1,2,4,8; DS only for 16,32) ----
    ex += lxor<1>(ex);  ey += lxor<1>(ey);  ez += lxor<1>(ez);
    ex += lxor<2>(ex);  ey += lxor<2>(ey);  ez += lxor<2>(ez);
    ex += lxor<4>(ex);  ey += lxor<4>(ey);  ez += lxor<4>(ez);
    ex += lxor<8>(ex);  ey += lxor<8>(ey);  ez += lxor<8>(ez);
    ex += lxor<16>(ex); ey += lxor<16>(ey); ez += lxor<16>(ez);
    ex += lxor<32>(ex); ey += lxor<32>(ey); ez += lxor<32>(ez);

    if (lane == 0) {
        float* o = out + 3 * (size_t)wave;
        o[0] = ex; o[1] = ey; o[2] = ez;
    }
}

extern "C" void kernel_launch(void* const* d_in, const int* in_sizes, int n_in,
                              void* d_out, int out_size, void* d_ws, size_t ws_size,
                              hipStream_t stream) {
    const float* patch   = (const float*)d_in[0];
    const float* weights = (const float*)d_in[1];
    float* out = (float*)d_out;
    float* ws  = (float*)d_ws;  // 2076 floats of tables

    int nstates = in_sizes[0] / 1024;  // 8192

    qk_setup<<<1, 1024, 0, stream>>>(weights, ws);

    int nblocks = nstates / 4;  // 4 waves (256 threads) per block
    qk_sim<<<nblocks, 256, 0, stream>>>(patch, ws, out, nstates);
}

// Round 5
// 82.631 us; speedup vs baseline: 1.1494x; 1.0398x over previous
//
#include <hip/hip_runtime.h>

// 10-qubit circuit: 10x Rot(phi,theta,omega) + CNOT ring + <X>,<Y>,<Z> on wire 0.
//
// Circuit = D_omega * RY_layer * D_phi on a REAL input. Since input is real, the
// state is two REAL vectors (u=x.cos(alpha), v=x.sin(alpha)) evolved by the same
// real RY layer -> amplitudes stored as v2f (re,im) and all gate math done with
// packed fp32 (v_pk_fma_f32, 2 FLOPs/inst on gfx90a+/gfx950).
//
// Layout (unchanged from R4, which validated the DS-pipe model: -8us matched the
// 172-removed-DS-ops prediction): one wave per state; lane holds 16 complex amps,
// slots s = h*4+q, idx = h*256 + lane*4 + q.
//   slot bit0=wire9, bit1=wire8, bit2=wire1, bit3=wire0  (in-register gates)
//   lane bit l = wire 7-l                                 (cross-lane gates)
// Measurement partner idx^0x300 = slot^12 (in-register, no shuffles).
// Cross-lane masks 1,2,4,8 via DPP (VALU pipe); only 16 (ds_swizzle) and
// 32 (ds_bpermute) on the per-CU DS pipe. DS ops/lane ~70, VALU ~620 packed.

typedef float v2f __attribute__((ext_vector_type(2)));

__device__ __forceinline__ v2f psplat(float k) { v2f r; r.x = k; r.y = k; return r; }
__device__ __forceinline__ v2f pfma(float k, v2f a, v2f b) {
    return __builtin_elementwise_fma(psplat(k), a, b);  // v_pk_fma_f32
}

template <int CTRL>
__device__ __forceinline__ float dppf(float x) {
    return __int_as_float(__builtin_amdgcn_update_dpp(
        __float_as_int(x), __float_as_int(x), CTRL, 0xF, 0xF, true));
}

template <int MASK>
__device__ __forceinline__ float lxor(float x) {
    if constexpr (MASK == 1)  return dppf<0xB1>(x);                   // quad_perm [1,0,3,2]
    else if constexpr (MASK == 2)  return dppf<0x4E>(x);              // quad_perm [2,3,0,1]
    else if constexpr (MASK == 4)  return dppf<0x141>(dppf<0x1B>(x)); // half_mirror o xor3
    else if constexpr (MASK == 8)  return dppf<0x128>(x);             // row_ror:8
    else if constexpr (MASK == 16)
        return __int_as_float(__builtin_amdgcn_ds_swizzle(__float_as_int(x), 0x401F));
    else return __shfl_xor(x, MASK, 64);
}

__global__ void qk_setup(const float* __restrict__ w, float* __restrict__ ws) {
    int t = threadIdx.x;  // 0..1023
    // P[2048] @0: e^{i alpha(idx)}, alpha = sum_w bit_w(idx)*phi_w (wire w <-> idx bit 9-w)
    float a = 0.f;
    for (int wq = 0; wq < 10; wq++)
        if ((t >> (9 - wq)) & 1) a += w[3 * wq];
    ws[2 * t]     = cosf(a);
    ws[2 * t + 1] = sinf(a);
    // CS[20] @2048: (cos(th/2), sin(th/2)) per wire
    if (t < 10) {
        float th = w[3 * t + 1];
        ws[2048 + 2 * t]     = cosf(0.5f * th);
        ws[2048 + 2 * t + 1] = sinf(0.5f * th);
    }
    // T4[8] @2068: h=(b9,b8); Delta = (1-2*b9)*omega0 + (1-2*b8)*omega1
    if (t < 4) {
        float d = (1.f - 2.f * ((t >> 1) & 1)) * w[2] + (1.f - 2.f * (t & 1)) * w[5];
        ws[2068 + 2 * t]     = cosf(d);
        ws[2068 + 2 * t + 1] = sinf(d);
    }
}

__device__ __forceinline__ void rgate(v2f (&amp)[16], int bit, float c, float s) {
#pragma unroll
    for (int s0 = 0; s0 < 16; s0++) {
        if (s0 & bit) continue;
        int s1 = s0 | bit;
        v2f a0 = amp[s0], a1 = amp[s1];
        amp[s0] = pfma(-s, a1, psplat(c) * a0);
        amp[s1] = pfma( s, a0, psplat(c) * a1);
    }
}

template <int MASK>
__device__ __forceinline__ void xgate(v2f (&amp)[16], float c, float ss) {
#pragma unroll
    for (int r = 0; r < 16; r++) {
        v2f p;
        p.x = lxor<MASK>(amp[r].x);
        p.y = lxor<MASK>(amp[r].y);
        amp[r] = pfma(ss, p, psplat(c) * amp[r]);
    }
}

__global__ __launch_bounds__(256) void qk_sim(const float* __restrict__ x,
                                              const float* __restrict__ ws,
                                              float* __restrict__ out,
                                              int nstates) {
    int wave = (int)((blockIdx.x * blockDim.x + threadIdx.x) >> 6);
    int lane = threadIdx.x & 63;

    const float* CS = ws + 2048;
    const float* T4 = ws + 2068;

    // ---- load + D_phi: amp[s] = x[idx] * e^{i alpha(idx)}  (packed mul) ----
    const float4* rowx = (const float4*)(x + (size_t)wave * 1024);
    const float4* Pt   = (const float4*)ws;  // (c,s) pairs -> 2 idx per float4
    v2f amp[16];
#pragma unroll
    for (int h = 0; h < 4; h++) {
        float4 v  = rowx[h * 64 + lane];
        float4 p0 = Pt[h * 128 + lane * 2];
        float4 p1 = Pt[h * 128 + lane * 2 + 1];
        v2f q0; q0.x = p0.x; q0.y = p0.y;
        v2f q1; q1.x = p0.z; q1.y = p0.w;
        v2f q2; q2.x = p1.x; q2.y = p1.y;
        v2f q3; q3.x = p1.z; q3.y = p1.w;
        amp[h * 4 + 0] = psplat(v.x) * q0;
        amp[h * 4 + 1] = psplat(v.y) * q1;
        amp[h * 4 + 2] = psplat(v.z) * q2;
        amp[h * 4 + 3] = psplat(v.w) * q3;
    }

    // ---- in-register RY: slot bit0=wire9, bit1=wire8, bit2=wire1, bit3=wire0 ----
    rgate(amp, 1, CS[2 * 9], CS[2 * 9 + 1]);
    rgate(amp, 2, CS[2 * 8], CS[2 * 8 + 1]);
    rgate(amp, 4, CS[2 * 1], CS[2 * 1 + 1]);
    rgate(amp, 8, CS[2 * 0], CS[2 * 0 + 1]);

    // ---- cross-lane RY: lane bit l -> wire 7-l ; bit=0: c*m - s*p, bit=1: c*m + s*p ----
    {
        float s7 = CS[2 * 7 + 1], s6 = CS[2 * 6 + 1], s5 = CS[2 * 5 + 1];
        float s4 = CS[2 * 4 + 1], s3 = CS[2 * 3 + 1], s2 = CS[2 * 2 + 1];
        xgate<1> (amp, CS[2 * 7], (lane & 1)  ? s7 : -s7);
        xgate<2> (amp, CS[2 * 6], (lane & 2)  ? s6 : -s6);
        xgate<4> (amp, CS[2 * 5], (lane & 4)  ? s5 : -s5);
        xgate<8> (amp, CS[2 * 4], (lane & 8)  ? s4 : -s4);
        xgate<16>(amp, CS[2 * 3], (lane & 16) ? s3 : -s3);
        xgate<32>(amp, CS[2 * 2], (lane & 32) ? s2 : -s2);
    }

    // ---- measurement: CNOT ring + D_omega folded; partner = slot^12 (in-register) ----
    float ex2 = 0.f, ey2 = 0.f;
    v2f ezv = psplat(0.f);
#pragma unroll
    for (int h = 0; h < 2; h++) {
        float cD = T4[2 * h], sD = T4[2 * h + 1];
#pragma unroll
        for (int q = 0; q < 4; q++) {
            int s  = h * 4 + q;
            int sp = s ^ 12;
            v2f m = amp[s], p = amp[sp];
            float cr = m.x * p.x + m.y * p.y;   // Re(conj(m)*p)
            float ci = m.x * p.y - m.y * p.x;   // Im(conj(m)*p)
            ex2 += cD * cr - sD * ci;
            float t = cD * ci + sD * cr;
            if ((h ^ (__popc(q) & 1)) & 1) ey2 -= t; else ey2 += t;
        }
    }
#pragma unroll
    for (int s = 0; s < 16; s++) {
        v2f n = amp[s] * amp[s];
        if ((((s >> 2) & 1) ^ (__popc(s & 3) & 1)) & 1) ezv -= n; else ezv += n;
    }
    float psgn = (__popc(lane) & 1) ? -1.f : 1.f;
    v2f exy;  // pack (ex, ey) so reduction adds go packed
    exy.x = 2.f * ex2;
    exy.y = 2.f * psgn * ey2;
    float ez = psgn * (ezv.x + ezv.y);

    // ---- wave reduction (DPP for 1,2,4,8; DS only for 16,32) ----
#define RED(M) { v2f o; o.x = lxor<M>(exy.x); o.y = lxor<M>(exy.y); exy += o; \
                 ez += lxor<M>(ez); }
    RED(1) RED(2) RED(4) RED(8) RED(16) RED(32)
#undef RED

    if (lane == 0) {
        float* o = out + 3 * (size_t)wave;
        o[0] = exy.x; o[1] = exy.y; o[2] = ez;
    }
}

extern "C" void kernel_launch(void* const* d_in, const int* in_sizes, int n_in,
                              void* d_out, int out_size, void* d_ws, size_t ws_size,
                              hipStream_t stream) {
    const float* patch   = (const float*)d_in[0];
    const float* weights = (const float*)d_in[1];
    float* out = (float*)d_out;
    float* ws  = (float*)d_ws;  // 2076 floats of tables

    int nstates = in_sizes[0] / 1024;  // 8192

    qk_setup<<<1, 1024, 0, stream>>>(weights, ws);

    int nblocks = nstates / 4;  // 4 waves (256 threads) per block, grid exact
    qk_sim<<<nblocks, 256, 0, stream>>>(patch, ws, out, nstates);
}

// Round 6
// 82.535 us; speedup vs baseline: 1.1508x; 1.0012x over previous
//
#include <hip/hip_runtime.h>

// 10-qubit circuit: 10x Rot(phi,theta,omega) + CNOT ring + <X>,<Y>,<Z> on wire 0.
//
// Circuit = D_omega * RY_layer * D_phi on a REAL input. State = two real vectors
// evolved by the same real RY layer -> amplitudes as v2f, math as v_pk_fma_f32.
//
// R6: SINGLE kernel. The R1-R5 setup kernel (~3-4us serial: launch + 1-block
// latency-bound table build) is folded in: every wave computes its own tables
// with fast trig (angles < 0.5 rad, __cosf/__sinf safe). Theta cos/sin via
// lanes 0..9 + v_readlane broadcast (VALU, not DS). Phase e^{i alpha} computed
// per-lane (32 trans) instead of 8 global_load_dwordx4 of a P table.
//
// Layout (validated R4: DS-pipe model, R5: packed fp32): one wave per state;
// lane holds 16 complex amps, slots s = h*4+q, idx = h*256 + lane*4 + q.
//   slot bit0=wire9, bit1=wire8, bit2=wire1, bit3=wire0  (in-register gates)
//   lane bit l = wire 7-l                                 (cross-lane gates)
// Measurement partner idx^0x300 = slot^12 (in-register, no shuffles).
// Cross-lane masks 1,2,4,8 via DPP (VALU pipe); only 16 (ds_swizzle) and
// 32 (ds_bpermute) on the per-CU DS pipe (~70 DS ops/lane).

typedef float v2f __attribute__((ext_vector_type(2)));

__device__ __forceinline__ v2f psplat(float k) { v2f r; r.x = k; r.y = k; return r; }
__device__ __forceinline__ v2f pfma(float k, v2f a, v2f b) {
    return __builtin_elementwise_fma(psplat(k), a, b);  // v_pk_fma_f32
}

template <int CTRL>
__device__ __forceinline__ float dppf(float x) {
    return __int_as_float(__builtin_amdgcn_update_dpp(
        __float_as_int(x), __float_as_int(x), CTRL, 0xF, 0xF, true));
}

template <int MASK>
__device__ __forceinline__ float lxor(float x) {
    if constexpr (MASK == 1)  return dppf<0xB1>(x);                   // quad_perm [1,0,3,2]
    else if constexpr (MASK == 2)  return dppf<0x4E>(x);              // quad_perm [2,3,0,1]
    else if constexpr (MASK == 4)  return dppf<0x141>(dppf<0x1B>(x)); // half_mirror o xor3
    else if constexpr (MASK == 8)  return dppf<0x128>(x);             // row_ror:8
    else if constexpr (MASK == 16)
        return __int_as_float(__builtin_amdgcn_ds_swizzle(__float_as_int(x), 0x401F));
    else return __shfl_xor(x, MASK, 64);
}

#define RLF(v, l) __int_as_float(__builtin_amdgcn_readlane(__float_as_int(v), (l)))

__device__ __forceinline__ void rgate(v2f (&amp)[16], int bit, float c, float s) {
#pragma unroll
    for (int s0 = 0; s0 < 16; s0++) {
        if (s0 & bit) continue;
        int s1 = s0 | bit;
        v2f a0 = amp[s0], a1 = amp[s1];
        amp[s0] = pfma(-s, a1, psplat(c) * a0);
        amp[s1] = pfma( s, a0, psplat(c) * a1);
    }
}

template <int MASK>
__device__ __forceinline__ void xgate(v2f (&amp)[16], float c, float ss) {
#pragma unroll
    for (int r = 0; r < 16; r++) {
        v2f p;
        p.x = lxor<MASK>(amp[r].x);
        p.y = lxor<MASK>(amp[r].y);
        amp[r] = pfma(ss, p, psplat(c) * amp[r]);
    }
}

__global__ __launch_bounds__(256) void qk_sim(const float* __restrict__ x,
                                              const float* __restrict__ w,
                                              float* __restrict__ out,
                                              int nstates) {
    int wave = (int)((blockIdx.x * blockDim.x + threadIdx.x) >> 6);
    int lane = threadIdx.x & 63;

    // ---- theta cos/sin: lanes 0..9 compute, broadcast via v_readlane ----
    int wi = (lane < 10) ? lane : 0;
    float thh = 0.5f * w[3 * wi + 1];
    float vc = __cosf(thh), vs = __sinf(thh);
    float c0 = RLF(vc, 0), s0 = RLF(vs, 0);
    float c1 = RLF(vc, 1), s1 = RLF(vs, 1);
    float c2 = RLF(vc, 2), s2 = RLF(vs, 2);
    float c3 = RLF(vc, 3), s3 = RLF(vs, 3);
    float c4 = RLF(vc, 4), s4 = RLF(vs, 4);
    float c5 = RLF(vc, 5), s5 = RLF(vs, 5);
    float c6 = RLF(vc, 6), s6 = RLF(vs, 6);
    float c7 = RLF(vc, 7), s7 = RLF(vs, 7);
    float c8 = RLF(vc, 8), s8 = RLF(vs, 8);
    float c9 = RLF(vc, 9), s9 = RLF(vs, 9);

    // ---- omega fold (uniform): d0 = w0+w1 omegas (h=0), d1 = w0-w1 (h=1) ----
    float om0 = w[2], om1 = w[5];
    float cD0 = __cosf(om0 + om1), sD0 = __sinf(om0 + om1);
    float cD1 = __cosf(om0 - om1), sD1 = __sinf(om0 - om1);

    // ---- phase angles: alpha(idx) = aL(lane) + aH(h) + aQ(q) ----
    // lane bit l -> wire 7-l (phi = w[3*(7-l)]); h: bit1->wire0, bit0->wire1;
    // q: bit1->wire8, bit0->wire9.
    float aL = 0.f;
    if (lane & 1)  aL += w[21];
    if (lane & 2)  aL += w[18];
    if (lane & 4)  aL += w[15];
    if (lane & 8)  aL += w[12];
    if (lane & 16) aL += w[9];
    if (lane & 32) aL += w[6];
    float pH = w[0], pHb = w[3];   // wire0, wire1
    float pQ = w[24], pQb = w[27]; // wire8, wire9
    float aH[4] = {0.f, pHb, pH, pH + pHb};
    float aQ[4] = {0.f, pQb, pQ, pQ + pQb};

    // ---- load + D_phi: amp[s] = x[idx] * e^{i alpha} ----
    const float4* rowx = (const float4*)(x + (size_t)wave * 1024);
    v2f amp[16];
#pragma unroll
    for (int h = 0; h < 4; h++) {
        float4 v = rowx[h * 64 + lane];
        float base = aL + aH[h];
        float xv[4] = {v.x, v.y, v.z, v.w};
#pragma unroll
        for (int q = 0; q < 4; q++) {
            float a = base + aQ[q];
            v2f e; e.x = __cosf(a); e.y = __sinf(a);
            amp[h * 4 + q] = psplat(xv[q]) * e;
        }
    }

    // ---- in-register RY: slot bit0=wire9, bit1=wire8, bit2=wire1, bit3=wire0 ----
    rgate(amp, 1, c9, s9);
    rgate(amp, 2, c8, s8);
    rgate(amp, 4, c1, s1);
    rgate(amp, 8, c0, s0);

    // ---- cross-lane RY: lane bit l -> wire 7-l ; bit=0: c*m - s*p, bit=1: +s*p ----
    xgate<1> (amp, c7, (lane & 1)  ? s7 : -s7);
    xgate<2> (amp, c6, (lane & 2)  ? s6 : -s6);
    xgate<4> (amp, c5, (lane & 4)  ? s5 : -s5);
    xgate<8> (amp, c4, (lane & 8)  ? s4 : -s4);
    xgate<16>(amp, c3, (lane & 16) ? s3 : -s3);
    xgate<32>(amp, c2, (lane & 32) ? s2 : -s2);

    // ---- measurement: CNOT ring + D_omega folded; partner = slot^12 ----
    float ex2 = 0.f, ey2 = 0.f;
    v2f ezv = psplat(0.f);
#pragma unroll
    for (int h = 0; h < 2; h++) {
        float cD = h ? cD1 : cD0;
        float sD = h ? sD1 : sD0;
#pragma unroll
        for (int q = 0; q < 4; q++) {
            int s  = h * 4 + q;
            int sp = s ^ 12;
            v2f m = amp[s], p = amp[sp];
            float cr = m.x * p.x + m.y * p.y;   // Re(conj(m)*p)
            float ci = m.x * p.y - m.y * p.x;   // Im(conj(m)*p)
            ex2 += cD * cr - sD * ci;
            float t = cD * ci + sD * cr;
            if ((h ^ (__popc(q) & 1)) & 1) ey2 -= t; else ey2 += t;
        }
    }
#pragma unroll
    for (int s = 0; s < 16; s++) {
        v2f n = amp[s] * amp[s];
        if ((((s >> 2) & 1) ^ (__popc(s & 3) & 1)) & 1) ezv -= n; else ezv += n;
    }
    float psgn = (__popc(lane) & 1) ? -1.f : 1.f;
    v2f exy;
    exy.x = 2.f * ex2;
    exy.y = 2.f * psgn * ey2;
    float ez = psgn * (ezv.x + ezv.y);

    // ---- wave reduction (DPP for 1,2,4,8; DS only for 16,32) ----
#define RED(M) { v2f o; o.x = lxor<M>(exy.x); o.y = lxor<M>(exy.y); exy += o; \
                 ez += lxor<M>(ez); }
    RED(1) RED(2) RED(4) RED(8) RED(16) RED(32)
#undef RED

    if (lane == 0) {
        float* o = out + 3 * (size_t)wave;
        o[0] = exy.x; o[1] = exy.y; o[2] = ez;
    }
}

extern "C" void kernel_launch(void* const* d_in, const int* in_sizes, int n_in,
                              void* d_out, int out_size, void* d_ws, size_t ws_size,
                              hipStream_t stream) {
    const float* patch   = (const float*)d_in[0];
    const float* weights = (const float*)d_in[1];
    float* out = (float*)d_out;

    int nstates = in_sizes[0] / 1024;  // 8192

    int nblocks = nstates / 4;  // 4 waves (256 threads) per block, grid exact
    qk_sim<<<nblocks, 256, 0, stream>>>(patch, weights, out, nstates);
}